// Round 11
// baseline (2549.504 us; speedup 1.0000x reference)
//
#include <hip/hip_runtime.h>

#define BN_EPS 1e-5f

// Activations in NCHW4c: elem(b,c,p) at [((b*(C/4) + c/4)*HW + p)*4 + (c&3)].
// Weights as given: [Cout][Cin][3][3]; 1x1 down weights [Cout][Cin].

// ---------------- stats prologue: [C][nPart] (sum,sumsq) -> smr[c]=(rstd, -mean*rstd)
template<int C>
__device__ __forceinline__ void stats_prologue(const float2* __restrict__ part,
                                               int nPart, float invN,
                                               float2* smr, float2* pred) {
  const int TPC = 256 / C;
  int c  = threadIdx.x / TPC;
  int sl = threadIdx.x - c * TPC;
  float s = 0.f, s2 = 0.f;
  for (int j = sl; j < nPart; j += TPC) {
    float2 p = part[c * nPart + j];
    s += p.x; s2 += p.y;
  }
  pred[threadIdx.x] = make_float2(s, s2);
  __syncthreads();
  for (int st = TPC >> 1; st; st >>= 1) {
    if (sl < st) {
      pred[threadIdx.x].x += pred[threadIdx.x + st].x;
      pred[threadIdx.x].y += pred[threadIdx.x + st].y;
    }
    __syncthreads();
  }
  if (sl == 0) {
    float m   = pred[threadIdx.x].x * invN;
    float var = fmaxf(pred[threadIdx.x].y * invN - m * m, 0.f);
    float r   = rsqrtf(var + BN_EPS);
    smr[c] = make_float2(r, -m * r);
  }
  __syncthreads();
}

// Virtual-input transform (in-bounds taps only; OOB taps stay 0 — activation
// precedes patch extraction, so zero padding contributes |0-w|):
//  0: a; 1: relu(bnA(a)); 2: relu(bnA(a)+b); 3: relu(bnA(a)+bnB(b));
//  4: relu(bnA(a)+relu(bnB(b)))
template<int INM>
__device__ __forceinline__ float xf(float a, float b, float2 tA, float2 tB) {
  if (INM == 0) return a;
  if (INM == 1) return fmaxf(fmaf(a, tA.x, tA.y), 0.f);
  if (INM == 2) return fmaxf(fmaf(a, tA.x, tA.y) + b, 0.f);
  if (INM == 3) return fmaxf(fmaf(a, tA.x, tA.y) + fmaf(b, tB.x, tB.y), 0.f);
  /* 4 */        return fmaxf(fmaf(a, tA.x, tA.y) + fmaxf(fmaf(b, tB.x, tB.y), 0.f), 0.f);
}

// ---------------- unified adder (all layers)
// Block = 256 thr = 4 waves x 64 positions. Wave zw handles ci-quads
// [zw*WQ, (zw+1)*WQ) (full Cin covered in-block); one co-quad per block.
// Grid 1D = nx * CoutQ, XCD-swizzled (contiguous pc-span per XCD, all coqs).
// LDS float4 reduce over waves; wave 0 writes raw (float4, fully coalesced,
// no partial-line RMW) + per-(block,channel) BN partials.
// DOWN: fused 1x1 stride-2 adder via always-valid center tap.
// HWRITE (stride-1, coq==0): each wave writes its transformed ci-quads to hout.
template<int CQ, int INM, bool DOWN, bool HWRITE>
__global__ void __launch_bounds__(256, 4)
adder_q(const float* __restrict__ A, const float* __restrict__ Bt,
        const float2* __restrict__ pA, int nPA,
        const float2* __restrict__ pB, int nPB, float invNin,
        const float* __restrict__ w, const float* __restrict__ wD,
        float* __restrict__ raw, float2* __restrict__ parts,
        float* __restrict__ rawD, float2* __restrict__ partsD,
        float* __restrict__ hout,
        int CoutQ, int H, int W, int Ho, int Wo, int stride, int pad, int nx) {
  constexpr int CIN = CQ * 4;
  constexpr int WQ  = CQ / 4;
  constexpr int UQ  = (WQ >= 2) ? 2 : 1;
  __shared__ float2 pred[256];
  __shared__ float2 smA[(INM >= 1) ? CIN : 1];
  __shared__ float2 smB[(INM >= 3) ? CIN : 1];
  __shared__ float4 sacc[4][64];
  __shared__ float4 saccD[DOWN ? 4 : 1][DOWN ? 64 : 1];
  if (INM >= 1) stats_prologue<CIN>(pA, nPA, invNin, smA, pred);
  if (INM >= 3) stats_prologue<CIN>(pB, nPB, invNin, smB, pred);

  const int id = blockIdx.x, span = nx >> 3;
  const int xcd = id & 7, slot = id >> 3;
  const int pc  = xcd * span + slot % span;
  const int coq = slot / span;

  const int HW = H * W, HWo = Ho * Wo;
  const int zw = threadIdx.x >> 6, pl = threadIdx.x & 63;
  const int i  = pc * 64 + pl;
  const int b  = i / HWo, hw = i - b * HWo;
  const int ho = hw / Wo, wo = hw - ho * Wo;

  int off[9]; bool val[9];
  #pragma unroll
  for (int kh = 0; kh < 3; kh++) {
    int hh = ho * stride + kh - pad;
    bool hv = (hh >= 0) & (hh < H);
    #pragma unroll
    for (int kw = 0; kw < 3; kw++) {
      int ww = wo * stride + kw - pad;
      val[kh * 3 + kw] = hv & (ww >= 0) & (ww < W);
      off[kh * 3 + kw] = hh * W + ww;
    }
  }

  float acc[4]  = {0.f, 0.f, 0.f, 0.f};
  float accD[4] = {0.f, 0.f, 0.f, 0.f};

  #pragma unroll
  for (int wq = 0; wq < WQ; wq += UQ) {
    float4 q[UQ][9];
    #pragma unroll
    for (int u = 0; u < UQ; u++) {
      const int cq = zw * WQ + wq + u;
      const float* Ab = A + (size_t)(b * CQ + cq) * HW * 4;
      const float* Bb = (INM >= 2) ? (Bt + (size_t)(b * CQ + cq) * HW * 4) : nullptr;
      float2 tA0, tA1, tA2, tA3, tB0, tB1, tB2, tB3;
      if (INM >= 1) { tA0 = smA[cq*4]; tA1 = smA[cq*4+1]; tA2 = smA[cq*4+2]; tA3 = smA[cq*4+3]; }
      if (INM >= 3) { tB0 = smB[cq*4]; tB1 = smB[cq*4+1]; tB2 = smB[cq*4+2]; tB3 = smB[cq*4+3]; }
      #pragma unroll
      for (int t = 0; t < 9; t++) {
        float4 a4 = make_float4(0.f, 0.f, 0.f, 0.f);
        if (val[t]) {
          a4 = *reinterpret_cast<const float4*>(Ab + (size_t)off[t] * 4);
          if (INM >= 1) {
            float4 b4 = make_float4(0.f, 0.f, 0.f, 0.f);
            if (INM >= 2) b4 = *reinterpret_cast<const float4*>(Bb + (size_t)off[t] * 4);
            a4.x = xf<INM>(a4.x, b4.x, tA0, tB0);
            a4.y = xf<INM>(a4.y, b4.y, tA1, tB1);
            a4.z = xf<INM>(a4.z, b4.z, tA2, tB2);
            a4.w = xf<INM>(a4.w, b4.w, tA3, tB3);
          }
        }
        q[u][t] = a4;
      }
      if (HWRITE) {
        if (coq == 0)
          *reinterpret_cast<float4*>(hout + ((size_t)(b * CQ + cq) * HW + hw) * 4) = q[u][4];
      }
    }
    #pragma unroll
    for (int c = 0; c < 4; c++) {
      #pragma unroll
      for (int u = 0; u < UQ; u++) {
        const int cq = zw * WQ + wq + u;
        const float* wp = w + ((coq * 4 + c) * CIN + cq * 4) * 9;   // wave-uniform
        float a = 0.f;
        #pragma unroll
        for (int t = 0; t < 9; t++) {
          a += fabsf(q[u][t].x - wp[t])      + fabsf(q[u][t].y - wp[9 + t])
             + fabsf(q[u][t].z - wp[18 + t]) + fabsf(q[u][t].w - wp[27 + t]);
        }
        acc[c] += a;
        if (DOWN) {
          const float* wd = wD + (coq * 4 + c) * CIN + cq * 4;
          accD[c] += fabsf(q[u][4].x - wd[0]) + fabsf(q[u][4].y - wd[1])
                   + fabsf(q[u][4].z - wd[2]) + fabsf(q[u][4].w - wd[3]);
        }
      }
    }
  }

  sacc[zw][pl] = make_float4(acc[0], acc[1], acc[2], acc[3]);
  if (DOWN) saccD[zw][pl] = make_float4(accD[0], accD[1], accD[2], accD[3]);
  __syncthreads();
  if (zw == 0) {
    float4 q0 = sacc[0][pl], q1 = sacc[1][pl], q2 = sacc[2][pl], q3 = sacc[3][pl];
    float4 v = make_float4(-(q0.x + q1.x + q2.x + q3.x), -(q0.y + q1.y + q2.y + q3.y),
                           -(q0.z + q1.z + q2.z + q3.z), -(q0.w + q1.w + q2.w + q3.w));
    *reinterpret_cast<float4*>(raw + ((size_t)(b * CoutQ + coq) * HWo + hw) * 4) = v;
    float s[4] = {v.x, v.y, v.z, v.w};
    #pragma unroll
    for (int c = 0; c < 4; c++) {
      float sx = s[c], sy = s[c] * s[c];
      #pragma unroll
      for (int o = 32; o; o >>= 1) { sx += __shfl_down(sx, o, 64); sy += __shfl_down(sy, o, 64); }
      if (pl == 0) parts[(coq * 4 + c) * nx + pc] = make_float2(sx, sy);
    }
    if (DOWN) {
      float4 d0 = saccD[0][pl], d1 = saccD[1][pl], d2 = saccD[2][pl], d3 = saccD[3][pl];
      float4 vd = make_float4(-(d0.x + d1.x + d2.x + d3.x), -(d0.y + d1.y + d2.y + d3.y),
                              -(d0.z + d1.z + d2.z + d3.z), -(d0.w + d1.w + d2.w + d3.w));
      *reinterpret_cast<float4*>(rawD + ((size_t)(b * CoutQ + coq) * HWo + hw) * 4) = vd;
      float sd[4] = {vd.x, vd.y, vd.z, vd.w};
      #pragma unroll
      for (int c = 0; c < 4; c++) {
        float sx = sd[c], sy = sd[c] * sd[c];
        #pragma unroll
        for (int o = 32; o; o >>= 1) { sx += __shfl_down(sx, o, 64); sy += __shfl_down(sy, o, 64); }
        if (pl == 0) partsD[(coq * 4 + c) * nx + pc] = make_float2(sx, sy);
      }
    }
  }
}

// ---------------- conv stem (NCHW in) -> NCHW4c raw + per-block BN partials [16][128]
__global__ void __launch_bounds__(256)
conv_stem_bn(const float* __restrict__ x, const float* __restrict__ w,
             float* __restrict__ raw, float2* __restrict__ partials) {
  const int i = blockIdx.x * 256 + threadIdx.x;   // position, b-major (32768)
  const int b = i >> 10, hw = i & 1023;
  const int ho = hw >> 5, wo = hw & 31;
  float xv[27];
  #pragma unroll
  for (int ci = 0; ci < 3; ci++) {
    const float* xp = x + (b * 3 + ci) * 1024;
    #pragma unroll
    for (int kh = 0; kh < 3; kh++) {
      int hh = ho + kh - 1;
      bool hv = (hh >= 0) & (hh < 32);
      #pragma unroll
      for (int kw = 0; kw < 3; kw++) {
        int ww = wo + kw - 1;
        xv[(ci * 3 + kh) * 3 + kw] = (hv & (ww >= 0) & (ww < 32)) ? xp[hh * 32 + ww] : 0.f;
      }
    }
  }
  float acc[16];
  #pragma unroll
  for (int co = 0; co < 16; co++) {
    float a = 0.f;
    const float* wp = w + co * 27;
    #pragma unroll
    for (int t = 0; t < 27; t++) a += xv[t] * wp[t];
    acc[co] = a;
  }
  #pragma unroll
  for (int cq = 0; cq < 4; cq++)
    *reinterpret_cast<float4*>(raw + ((size_t)(b * 4 + cq) * 1024 + hw) * 4) =
        make_float4(acc[cq * 4], acc[cq * 4 + 1], acc[cq * 4 + 2], acc[cq * 4 + 3]);

  __shared__ float2 red[4][16];
  const int lane = threadIdx.x & 63, wid = threadIdx.x >> 6;
  #pragma unroll
  for (int co = 0; co < 16; co++) {
    float sx = acc[co], sy = acc[co] * acc[co];
    #pragma unroll
    for (int o = 32; o; o >>= 1) { sx += __shfl_down(sx, o, 64); sy += __shfl_down(sy, o, 64); }
    if (lane == 0) red[wid][co] = make_float2(sx, sy);
  }
  __syncthreads();
  if (threadIdx.x < 16) {
    float2 t = red[0][threadIdx.x];
    #pragma unroll
    for (int wv = 1; wv < 4; wv++) { t.x += red[wv][threadIdx.x].x; t.y += red[wv][threadIdx.x].y; }
    partials[threadIdx.x * 128 + blockIdx.x] = t;
  }
}

// ---------------- final combine + per-image pool (NCHW4c in, grid 32 = images)
__global__ void __launch_bounds__(256)
pool_combine(const float* __restrict__ raw2, const float2* __restrict__ part2,
             const float* __restrict__ idsrc, float invN, float* __restrict__ pooled) {
  __shared__ float2 s2[64];
  __shared__ float2 pred[256];
  __shared__ float4 s4[16][16];
  stats_prologue<64>(part2, 32, invN, s2, pred);
  const int b = blockIdx.x, cq = threadIdx.x & 15, pg = threadIdx.x >> 4;
  float2 t0 = s2[cq * 4], t1 = s2[cq * 4 + 1], t2 = s2[cq * 4 + 2], t3 = s2[cq * 4 + 3];
  float4 sum = make_float4(0.f, 0.f, 0.f, 0.f);
  #pragma unroll
  for (int k = 0; k < 4; k++) {
    int pos = pg * 4 + k;
    size_t idx = ((size_t)(b * 16 + cq) * 64 + pos) * 4;
    float4 r = *reinterpret_cast<const float4*>(raw2 + idx);
    float4 d = *reinterpret_cast<const float4*>(idsrc + idx);
    sum.x += fmaxf(fmaf(r.x, t0.x, t0.y) + d.x, 0.f);
    sum.y += fmaxf(fmaf(r.y, t1.x, t1.y) + d.y, 0.f);
    sum.z += fmaxf(fmaf(r.z, t2.x, t2.y) + d.z, 0.f);
    sum.w += fmaxf(fmaf(r.w, t3.x, t3.y) + d.w, 0.f);
  }
  s4[pg][cq] = sum;
  __syncthreads();
  if (threadIdx.x < 64) {
    const int c = threadIdx.x, cq2 = c >> 2, j = c & 3;
    float s = 0.f;
    #pragma unroll
    for (int g = 0; g < 16; g++) {
      float4 t = s4[g][cq2];
      s += (j == 0) ? t.x : (j == 1) ? t.y : (j == 2) ? t.z : t.w;
    }
    pooled[b * 64 + c] = s * (1.f / 64.f);
  }
}

// ---------------- head
__global__ void head_k(const float* __restrict__ pooled, const float* __restrict__ fcw,
                       float* __restrict__ out) {
  __shared__ float logits[320];
  __shared__ float mn[10], rs[10];
  int t = threadIdx.x;
  if (t < 320) {
    int b = t / 10, o = t - b * 10;
    float s = 0.f;
    #pragma unroll
    for (int c = 0; c < 64; c++) s += pooled[b * 64 + c] * fcw[o * 64 + c];
    logits[t] = s;
  }
  __syncthreads();
  if (t < 10) {
    float s = 0.f;
    for (int b = 0; b < 32; b++) s += logits[b * 10 + t];
    float m = s * (1.f / 32.f);
    float v = 0.f;
    for (int b = 0; b < 32; b++) { float d = logits[b * 10 + t] - m; v += d * d; }
    mn[t] = m;
    rs[t] = rsqrtf(v * (1.f / 32.f) + BN_EPS);
  }
  __syncthreads();
  if (t < 320) out[t] = (logits[t] - mn[t % 10]) * rs[t % 10];
}

// ================================================================ host
extern "C" void kernel_launch(void* const* d_in, const int* in_sizes, int n_in,
                              void* d_out, int out_size, void* d_ws, size_t ws_size,
                              hipStream_t stream) {
  const float* x      = (const float*)d_in[0];
  const float* conv1w = (const float*)d_in[1];
  const float* l1w    = (const float*)d_in[2];
  const float* l2w0   = (const float*)d_in[3];
  const float* l2ws   = (const float*)d_in[4];
  const float* l2down = (const float*)d_in[5];
  const float* l3w0   = (const float*)d_in[6];
  const float* l3ws   = (const float*)d_in[7];
  const float* l3down = (const float*)d_in[8];
  const float* fcw    = (const float*)d_in[9];
  float* out = (float*)d_out;

  const int S = 524288;                    // 2 MB in floats
  float* base = (float*)d_ws;
  float* R0  = base + 0 * S;               // stem raw
  float* RA  = base + 1 * S;               // a1 raw (transient)
  float* RB0 = base + 2 * S;               // a2 raw dbuf
  float* RB1 = base + 3 * S;
  float* HA  = base + 4 * S;               // h dbuf
  float* HB  = base + 5 * S;
  float* RD  = base + 6 * S;               // down raw
  float* pooled = base + 7 * S;            // 2048
  float2* partS  = (float2*)(pooled + 4096);  // [16][128]
  float2* partA  = partS  + 8192;             // up to [16][512]
  float2* partB0 = partA  + 8192;
  float2* partB1 = partB0 + 8192;
  float2* partD  = partB1 + 8192;

  const float inv1 = 1.f / 32768.f, inv2 = 1.f / 8192.f, inv3 = 1.f / 2048.f;
  const int nx1 = 512, nx2 = 128, nx3 = 32;          // B*HWo/64
  const int G1 = nx1 * 4, G2 = nx2 * 8, G3 = nx3 * 16;  // 2048 / 1024 / 512

  // 1. stem
  conv_stem_bn<<<128, 256, 0, stream>>>(x, conv1w, R0, partS);

  // ---- layer1 (CQ=4, CoutQ=4, 32x32)
  adder_q<4,1,false,false><<<G1,256,0,stream>>>(R0, nullptr, partS, 128, nullptr, 0, inv1,
      l1w + 0*2304, nullptr, RA, partA, nullptr, nullptr, nullptr, 4, 32,32,32,32, 1,1, nx1);
  adder_q<4,1,false,false><<<G1,256,0,stream>>>(RA, nullptr, partA, nx1, nullptr, 0, inv1,
      l1w + 1*2304, nullptr, RB0, partB0, nullptr, nullptr, nullptr, 4, 32,32,32,32, 1,1, nx1);
  adder_q<4,4,false,true ><<<G1,256,0,stream>>>(RB0, R0, partB0, nx1, partS, 128, inv1,
      l1w + 2*2304, nullptr, RA, partA, nullptr, nullptr, HA, 4, 32,32,32,32, 1,1, nx1);
  adder_q<4,1,false,false><<<G1,256,0,stream>>>(RA, nullptr, partA, nx1, nullptr, 0, inv1,
      l1w + 3*2304, nullptr, RB1, partB1, nullptr, nullptr, nullptr, 4, 32,32,32,32, 1,1, nx1);
  adder_q<4,2,false,true ><<<G1,256,0,stream>>>(RB1, HA, partB1, nx1, nullptr, 0, inv1,
      l1w + 4*2304, nullptr, RA, partA, nullptr, nullptr, HB, 4, 32,32,32,32, 1,1, nx1);
  adder_q<4,1,false,false><<<G1,256,0,stream>>>(RA, nullptr, partA, nx1, nullptr, 0, inv1,
      l1w + 5*2304, nullptr, RB0, partB0, nullptr, nullptr, nullptr, 4, 32,32,32,32, 1,1, nx1);

  // ---- layer2 (CoutQ=8, 16x16)
  adder_q<4,2,true ,false><<<G2,256,0,stream>>>(RB0, HB, partB0, nx1, nullptr, 0, inv1,
      l2w0, l2down, RA, partA, RD, partD, nullptr, 8, 32,32,16,16, 2,1, nx2);
  adder_q<8,1,false,false><<<G2,256,0,stream>>>(RA, nullptr, partA, nx2, nullptr, 0, inv2,
      l2ws + 0*9216, nullptr, RB1, partB1, nullptr, nullptr, nullptr, 8, 16,16,16,16, 1,1, nx2);
  adder_q<8,3,false,true ><<<G2,256,0,stream>>>(RB1, RD, partB1, nx2, partD, nx2, inv2,
      l2ws + 1*9216, nullptr, RA, partA, nullptr, nullptr, HA, 8, 16,16,16,16, 1,1, nx2);
  adder_q<8,1,false,false><<<G2,256,0,stream>>>(RA, nullptr, partA, nx2, nullptr, 0, inv2,
      l2ws + 2*9216, nullptr, RB0, partB0, nullptr, nullptr, nullptr, 8, 16,16,16,16, 1,1, nx2);
  adder_q<8,2,false,true ><<<G2,256,0,stream>>>(RB0, HA, partB0, nx2, nullptr, 0, inv2,
      l2ws + 3*9216, nullptr, RA, partA, nullptr, nullptr, HB, 8, 16,16,16,16, 1,1, nx2);
  adder_q<8,1,false,false><<<G2,256,0,stream>>>(RA, nullptr, partA, nx2, nullptr, 0, inv2,
      l2ws + 4*9216, nullptr, RB1, partB1, nullptr, nullptr, nullptr, 8, 16,16,16,16, 1,1, nx2);

  // ---- layer3 (CoutQ=16, 8x8)
  adder_q<8,2,true ,false><<<G3,256,0,stream>>>(RB1, HB, partB1, nx2, nullptr, 0, inv2,
      l3w0, l3down, RA, partA, RD, partD, nullptr, 16, 16,16,8,8, 2,1, nx3);
  adder_q<16,1,false,false><<<G3,256,0,stream>>>(RA, nullptr, partA, nx3, nullptr, 0, inv3,
      l3ws + 0*36864, nullptr, RB0, partB0, nullptr, nullptr, nullptr, 16, 8,8,8,8, 1,1, nx3);
  adder_q<16,3,false,true ><<<G3,256,0,stream>>>(RB0, RD, partB0, nx3, partD, nx3, inv3,
      l3ws + 1*36864, nullptr, RA, partA, nullptr, nullptr, HA, 16, 8,8,8,8, 1,1, nx3);
  adder_q<16,1,false,false><<<G3,256,0,stream>>>(RA, nullptr, partA, nx3, nullptr, 0, inv3,
      l3ws + 2*36864, nullptr, RB1, partB1, nullptr, nullptr, nullptr, 16, 8,8,8,8, 1,1, nx3);
  adder_q<16,2,false,true ><<<G3,256,0,stream>>>(RB1, HA, partB1, nx3, nullptr, 0, inv3,
      l3ws + 3*36864, nullptr, RA, partA, nullptr, nullptr, HB, 16, 8,8,8,8, 1,1, nx3);
  adder_q<16,1,false,false><<<G3,256,0,stream>>>(RA, nullptr, partA, nx3, nullptr, 0, inv3,
      l3ws + 4*36864, nullptr, RB0, partB0, nullptr, nullptr, nullptr, 16, 8,8,8,8, 1,1, nx3);

  // final combine + pool, head
  pool_combine<<<32, 256, 0, stream>>>(RB0, partB0, HB, inv3, pooled);
  head_k<<<1, 320, 0, stream>>>(pooled, fcw, out);
}

// Round 12
// 949.423 us; speedup vs baseline: 2.6853x; 2.6853x over previous
//
#include <hip/hip_runtime.h>

#define BN_EPS 1e-5f

// Activations in NCHW4c: elem(b,c,p) at [((b*(C/4) + c/4)*HW + p)*4 + (c&3)].
// Weights as given: [Cout][Cin][3][3]; 1x1 down weights [Cout][Cin].

// ---------------- stats prologue: [C][nPart] (sum,sumsq) -> smr[c]=(rstd, -mean*rstd)
template<int C>
__device__ __forceinline__ void stats_prologue(const float2* __restrict__ part,
                                               int nPart, float invN,
                                               float2* smr, float2* pred) {
  const int TPC = 256 / C;
  int c  = threadIdx.x / TPC;
  int sl = threadIdx.x - c * TPC;
  float s = 0.f, s2 = 0.f;
  for (int j = sl; j < nPart; j += TPC) {
    float2 p = part[c * nPart + j];
    s += p.x; s2 += p.y;
  }
  pred[threadIdx.x] = make_float2(s, s2);
  __syncthreads();
  for (int st = TPC >> 1; st; st >>= 1) {
    if (sl < st) {
      pred[threadIdx.x].x += pred[threadIdx.x + st].x;
      pred[threadIdx.x].y += pred[threadIdx.x + st].y;
    }
    __syncthreads();
  }
  if (sl == 0) {
    float m   = pred[threadIdx.x].x * invN;
    float var = fmaxf(pred[threadIdx.x].y * invN - m * m, 0.f);
    float r   = rsqrtf(var + BN_EPS);
    smr[c] = make_float2(r, -m * r);
  }
  __syncthreads();
}

// Virtual-input transform (in-bounds taps only; OOB taps stay 0 — activation
// precedes patch extraction, so zero padding contributes |0-w|):
//  0: a; 1: relu(bnA(a)); 2: relu(bnA(a)+b); 3: relu(bnA(a)+bnB(b));
//  4: relu(bnA(a)+relu(bnB(b)))
template<int INM>
__device__ __forceinline__ float xf(float a, float b, float2 tA, float2 tB) {
  if (INM == 0) return a;
  if (INM == 1) return fmaxf(fmaf(a, tA.x, tA.y), 0.f);
  if (INM == 2) return fmaxf(fmaf(a, tA.x, tA.y) + b, 0.f);
  if (INM == 3) return fmaxf(fmaf(a, tA.x, tA.y) + fmaf(b, tB.x, tB.y), 0.f);
  /* 4 */        return fmaxf(fmaf(a, tA.x, tA.y) + fmaxf(fmaf(b, tB.x, tB.y), 0.f), 0.f);
}

// ---------------- unified adder (all layers)
// Block = 256 thr = 4 waves x 64 positions. Wave zw handles ci-quads
// [zw*WQ, (zw+1)*WQ) one quad per iteration (#pragma unroll 1: exactly one
// q[9] float4 patch live -> no scratch spill). One co-quad per block.
// Grid 1D = nx * CoutQ, XCD-swizzled (contiguous pc-span per XCD, all coqs).
// LDS float4 reduce over waves; wave 0 writes raw (float4, coalesced) +
// per-(block,channel) BN partials.
// DOWN: fused 1x1 stride-2 adder via always-valid center tap.
// HWRITE (stride-1, coq==0): each wave writes its transformed ci-quads to hout.
template<int CQ, int INM, bool DOWN, bool HWRITE>
__global__ void __launch_bounds__(256, 4)
adder_q(const float* __restrict__ A, const float* __restrict__ Bt,
        const float2* __restrict__ pA, int nPA,
        const float2* __restrict__ pB, int nPB, float invNin,
        const float* __restrict__ w, const float* __restrict__ wD,
        float* __restrict__ raw, float2* __restrict__ parts,
        float* __restrict__ rawD, float2* __restrict__ partsD,
        float* __restrict__ hout,
        int CoutQ, int H, int W, int Ho, int Wo, int stride, int pad, int nx) {
  constexpr int CIN = CQ * 4;
  constexpr int WQ  = CQ / 4;
  __shared__ float2 pred[256];
  __shared__ float2 smA[(INM >= 1) ? CIN : 1];
  __shared__ float2 smB[(INM >= 3) ? CIN : 1];
  __shared__ float4 sacc[4][64];
  __shared__ float4 saccD[DOWN ? 4 : 1][DOWN ? 64 : 1];
  if (INM >= 1) stats_prologue<CIN>(pA, nPA, invNin, smA, pred);
  if (INM >= 3) stats_prologue<CIN>(pB, nPB, invNin, smB, pred);

  const int id = blockIdx.x, span = nx >> 3;
  const int xcd = id & 7, slot = id >> 3;
  const int pc  = xcd * span + slot % span;
  const int coq = slot / span;

  const int HW = H * W, HWo = Ho * Wo;
  const int zw = threadIdx.x >> 6, pl = threadIdx.x & 63;
  const int i  = pc * 64 + pl;
  const int b  = i / HWo, hw = i - b * HWo;
  const int ho = hw / Wo, wo = hw - ho * Wo;

  int off[9]; bool val[9];
  #pragma unroll
  for (int kh = 0; kh < 3; kh++) {
    int hh = ho * stride + kh - pad;
    bool hv = (hh >= 0) & (hh < H);
    #pragma unroll
    for (int kw = 0; kw < 3; kw++) {
      int ww = wo * stride + kw - pad;
      val[kh * 3 + kw] = hv & (ww >= 0) & (ww < W);
      off[kh * 3 + kw] = hh * W + ww;
    }
  }

  float acc[4]  = {0.f, 0.f, 0.f, 0.f};
  float accD[4] = {0.f, 0.f, 0.f, 0.f};

  #pragma unroll 1
  for (int wq = 0; wq < WQ; wq++) {
    const int cq = zw * WQ + wq;
    const float* Ab = A + (size_t)(b * CQ + cq) * HW * 4;
    const float* Bb = (INM >= 2) ? (Bt + (size_t)(b * CQ + cq) * HW * 4) : nullptr;
    float2 tA0, tA1, tA2, tA3, tB0, tB1, tB2, tB3;
    if (INM >= 1) { tA0 = smA[cq*4]; tA1 = smA[cq*4+1]; tA2 = smA[cq*4+2]; tA3 = smA[cq*4+3]; }
    if (INM >= 3) { tB0 = smB[cq*4]; tB1 = smB[cq*4+1]; tB2 = smB[cq*4+2]; tB3 = smB[cq*4+3]; }
    float4 q[9];
    #pragma unroll
    for (int t = 0; t < 9; t++) {
      float4 a4 = make_float4(0.f, 0.f, 0.f, 0.f);
      if (val[t]) {
        a4 = *reinterpret_cast<const float4*>(Ab + (size_t)off[t] * 4);
        if (INM >= 1) {
          float4 b4 = make_float4(0.f, 0.f, 0.f, 0.f);
          if (INM >= 2) b4 = *reinterpret_cast<const float4*>(Bb + (size_t)off[t] * 4);
          a4.x = xf<INM>(a4.x, b4.x, tA0, tB0);
          a4.y = xf<INM>(a4.y, b4.y, tA1, tB1);
          a4.z = xf<INM>(a4.z, b4.z, tA2, tB2);
          a4.w = xf<INM>(a4.w, b4.w, tA3, tB3);
        }
      }
      q[t] = a4;
    }
    if (HWRITE) {
      if (coq == 0)
        *reinterpret_cast<float4*>(hout + ((size_t)(b * CQ + cq) * HW + hw) * 4) = q[4];
    }
    #pragma unroll
    for (int c = 0; c < 4; c++) {
      const float* wp = w + ((coq * 4 + c) * CIN + cq * 4) * 9;   // wave-uniform
      float a = 0.f;
      #pragma unroll
      for (int t = 0; t < 9; t++) {
        a += fabsf(q[t].x - wp[t])      + fabsf(q[t].y - wp[9 + t])
           + fabsf(q[t].z - wp[18 + t]) + fabsf(q[t].w - wp[27 + t]);
      }
      acc[c] += a;
      if (DOWN) {
        const float* wd = wD + (coq * 4 + c) * CIN + cq * 4;
        accD[c] += fabsf(q[4].x - wd[0]) + fabsf(q[4].y - wd[1])
                 + fabsf(q[4].z - wd[2]) + fabsf(q[4].w - wd[3]);
      }
    }
  }

  sacc[zw][pl] = make_float4(acc[0], acc[1], acc[2], acc[3]);
  if (DOWN) saccD[zw][pl] = make_float4(accD[0], accD[1], accD[2], accD[3]);
  __syncthreads();
  if (zw == 0) {
    float4 q0 = sacc[0][pl], q1 = sacc[1][pl], q2 = sacc[2][pl], q3 = sacc[3][pl];
    float4 v = make_float4(-(q0.x + q1.x + q2.x + q3.x), -(q0.y + q1.y + q2.y + q3.y),
                           -(q0.z + q1.z + q2.z + q3.z), -(q0.w + q1.w + q2.w + q3.w));
    *reinterpret_cast<float4*>(raw + ((size_t)(b * CoutQ + coq) * HWo + hw) * 4) = v;
    float s[4] = {v.x, v.y, v.z, v.w};
    #pragma unroll
    for (int c = 0; c < 4; c++) {
      float sx = s[c], sy = s[c] * s[c];
      #pragma unroll
      for (int o = 32; o; o >>= 1) { sx += __shfl_down(sx, o, 64); sy += __shfl_down(sy, o, 64); }
      if (pl == 0) parts[(coq * 4 + c) * nx + pc] = make_float2(sx, sy);
    }
    if (DOWN) {
      float4 d0 = saccD[0][pl], d1 = saccD[1][pl], d2 = saccD[2][pl], d3 = saccD[3][pl];
      float4 vd = make_float4(-(d0.x + d1.x + d2.x + d3.x), -(d0.y + d1.y + d2.y + d3.y),
                              -(d0.z + d1.z + d2.z + d3.z), -(d0.w + d1.w + d2.w + d3.w));
      *reinterpret_cast<float4*>(rawD + ((size_t)(b * CoutQ + coq) * HWo + hw) * 4) = vd;
      float sd[4] = {vd.x, vd.y, vd.z, vd.w};
      #pragma unroll
      for (int c = 0; c < 4; c++) {
        float sx = sd[c], sy = sd[c] * sd[c];
        #pragma unroll
        for (int o = 32; o; o >>= 1) { sx += __shfl_down(sx, o, 64); sy += __shfl_down(sy, o, 64); }
        if (pl == 0) partsD[(coq * 4 + c) * nx + pc] = make_float2(sx, sy);
      }
    }
  }
}

// ---------------- conv stem (NCHW in) -> NCHW4c raw + per-block BN partials [16][128]
__global__ void __launch_bounds__(256)
conv_stem_bn(const float* __restrict__ x, const float* __restrict__ w,
             float* __restrict__ raw, float2* __restrict__ partials) {
  const int i = blockIdx.x * 256 + threadIdx.x;   // position, b-major (32768)
  const int b = i >> 10, hw = i & 1023;
  const int ho = hw >> 5, wo = hw & 31;
  float xv[27];
  #pragma unroll
  for (int ci = 0; ci < 3; ci++) {
    const float* xp = x + (b * 3 + ci) * 1024;
    #pragma unroll
    for (int kh = 0; kh < 3; kh++) {
      int hh = ho + kh - 1;
      bool hv = (hh >= 0) & (hh < 32);
      #pragma unroll
      for (int kw = 0; kw < 3; kw++) {
        int ww = wo + kw - 1;
        xv[(ci * 3 + kh) * 3 + kw] = (hv & (ww >= 0) & (ww < 32)) ? xp[hh * 32 + ww] : 0.f;
      }
    }
  }
  float acc[16];
  #pragma unroll
  for (int co = 0; co < 16; co++) {
    float a = 0.f;
    const float* wp = w + co * 27;
    #pragma unroll
    for (int t = 0; t < 27; t++) a += xv[t] * wp[t];
    acc[co] = a;
  }
  #pragma unroll
  for (int cq = 0; cq < 4; cq++)
    *reinterpret_cast<float4*>(raw + ((size_t)(b * 4 + cq) * 1024 + hw) * 4) =
        make_float4(acc[cq * 4], acc[cq * 4 + 1], acc[cq * 4 + 2], acc[cq * 4 + 3]);

  __shared__ float2 red[4][16];
  const int lane = threadIdx.x & 63, wid = threadIdx.x >> 6;
  #pragma unroll
  for (int co = 0; co < 16; co++) {
    float sx = acc[co], sy = acc[co] * acc[co];
    #pragma unroll
    for (int o = 32; o; o >>= 1) { sx += __shfl_down(sx, o, 64); sy += __shfl_down(sy, o, 64); }
    if (lane == 0) red[wid][co] = make_float2(sx, sy);
  }
  __syncthreads();
  if (threadIdx.x < 16) {
    float2 t = red[0][threadIdx.x];
    #pragma unroll
    for (int wv = 1; wv < 4; wv++) { t.x += red[wv][threadIdx.x].x; t.y += red[wv][threadIdx.x].y; }
    partials[threadIdx.x * 128 + blockIdx.x] = t;
  }
}

// ---------------- final combine + per-image pool (NCHW4c in, grid 32 = images)
__global__ void __launch_bounds__(256)
pool_combine(const float* __restrict__ raw2, const float2* __restrict__ part2,
             const float* __restrict__ idsrc, float invN, float* __restrict__ pooled) {
  __shared__ float2 s2[64];
  __shared__ float2 pred[256];
  __shared__ float4 s4[16][16];
  stats_prologue<64>(part2, 32, invN, s2, pred);
  const int b = blockIdx.x, cq = threadIdx.x & 15, pg = threadIdx.x >> 4;
  float2 t0 = s2[cq * 4], t1 = s2[cq * 4 + 1], t2 = s2[cq * 4 + 2], t3 = s2[cq * 4 + 3];
  float4 sum = make_float4(0.f, 0.f, 0.f, 0.f);
  #pragma unroll
  for (int k = 0; k < 4; k++) {
    int pos = pg * 4 + k;
    size_t idx = ((size_t)(b * 16 + cq) * 64 + pos) * 4;
    float4 r = *reinterpret_cast<const float4*>(raw2 + idx);
    float4 d = *reinterpret_cast<const float4*>(idsrc + idx);
    sum.x += fmaxf(fmaf(r.x, t0.x, t0.y) + d.x, 0.f);
    sum.y += fmaxf(fmaf(r.y, t1.x, t1.y) + d.y, 0.f);
    sum.z += fmaxf(fmaf(r.z, t2.x, t2.y) + d.z, 0.f);
    sum.w += fmaxf(fmaf(r.w, t3.x, t3.y) + d.w, 0.f);
  }
  s4[pg][cq] = sum;
  __syncthreads();
  if (threadIdx.x < 64) {
    const int c = threadIdx.x, cq2 = c >> 2, j = c & 3;
    float s = 0.f;
    #pragma unroll
    for (int g = 0; g < 16; g++) {
      float4 t = s4[g][cq2];
      s += (j == 0) ? t.x : (j == 1) ? t.y : (j == 2) ? t.z : t.w;
    }
    pooled[b * 64 + c] = s * (1.f / 64.f);
  }
}

// ---------------- head
__global__ void head_k(const float* __restrict__ pooled, const float* __restrict__ fcw,
                       float* __restrict__ out) {
  __shared__ float logits[320];
  __shared__ float mn[10], rs[10];
  int t = threadIdx.x;
  if (t < 320) {
    int b = t / 10, o = t - b * 10;
    float s = 0.f;
    #pragma unroll
    for (int c = 0; c < 64; c++) s += pooled[b * 64 + c] * fcw[o * 64 + c];
    logits[t] = s;
  }
  __syncthreads();
  if (t < 10) {
    float s = 0.f;
    for (int b = 0; b < 32; b++) s += logits[b * 10 + t];
    float m = s * (1.f / 32.f);
    float v = 0.f;
    for (int b = 0; b < 32; b++) { float d = logits[b * 10 + t] - m; v += d * d; }
    mn[t] = m;
    rs[t] = rsqrtf(v * (1.f / 32.f) + BN_EPS);
  }
  __syncthreads();
  if (t < 320) out[t] = (logits[t] - mn[t % 10]) * rs[t % 10];
}

// ================================================================ host
extern "C" void kernel_launch(void* const* d_in, const int* in_sizes, int n_in,
                              void* d_out, int out_size, void* d_ws, size_t ws_size,
                              hipStream_t stream) {
  const float* x      = (const float*)d_in[0];
  const float* conv1w = (const float*)d_in[1];
  const float* l1w    = (const float*)d_in[2];
  const float* l2w0   = (const float*)d_in[3];
  const float* l2ws   = (const float*)d_in[4];
  const float* l2down = (const float*)d_in[5];
  const float* l3w0   = (const float*)d_in[6];
  const float* l3ws   = (const float*)d_in[7];
  const float* l3down = (const float*)d_in[8];
  const float* fcw    = (const float*)d_in[9];
  float* out = (float*)d_out;

  const int S = 524288;                    // 2 MB in floats
  float* base = (float*)d_ws;
  float* R0  = base + 0 * S;               // stem raw
  float* RA  = base + 1 * S;               // a1 raw (transient)
  float* RB0 = base + 2 * S;               // a2 raw dbuf
  float* RB1 = base + 3 * S;
  float* HA  = base + 4 * S;               // h dbuf
  float* HB  = base + 5 * S;
  float* RD  = base + 6 * S;               // down raw
  float* pooled = base + 7 * S;            // 2048
  float2* partS  = (float2*)(pooled + 4096);  // [16][128]
  float2* partA  = partS  + 8192;             // up to [16][512]
  float2* partB0 = partA  + 8192;
  float2* partB1 = partB0 + 8192;
  float2* partD  = partB1 + 8192;

  const float inv1 = 1.f / 32768.f, inv2 = 1.f / 8192.f, inv3 = 1.f / 2048.f;
  const int nx1 = 512, nx2 = 128, nx3 = 32;             // B*HWo/64
  const int G1 = nx1 * 4, G2 = nx2 * 8, G3 = nx3 * 16;  // 2048 / 1024 / 512

  // 1. stem
  conv_stem_bn<<<128, 256, 0, stream>>>(x, conv1w, R0, partS);

  // ---- layer1 (CQ=4, CoutQ=4, 32x32)
  adder_q<4,1,false,false><<<G1,256,0,stream>>>(R0, nullptr, partS, 128, nullptr, 0, inv1,
      l1w + 0*2304, nullptr, RA, partA, nullptr, nullptr, nullptr, 4, 32,32,32,32, 1,1, nx1);
  adder_q<4,1,false,false><<<G1,256,0,stream>>>(RA, nullptr, partA, nx1, nullptr, 0, inv1,
      l1w + 1*2304, nullptr, RB0, partB0, nullptr, nullptr, nullptr, 4, 32,32,32,32, 1,1, nx1);
  adder_q<4,4,false,true ><<<G1,256,0,stream>>>(RB0, R0, partB0, nx1, partS, 128, inv1,
      l1w + 2*2304, nullptr, RA, partA, nullptr, nullptr, HA, 4, 32,32,32,32, 1,1, nx1);
  adder_q<4,1,false,false><<<G1,256,0,stream>>>(RA, nullptr, partA, nx1, nullptr, 0, inv1,
      l1w + 3*2304, nullptr, RB1, partB1, nullptr, nullptr, nullptr, 4, 32,32,32,32, 1,1, nx1);
  adder_q<4,2,false,true ><<<G1,256,0,stream>>>(RB1, HA, partB1, nx1, nullptr, 0, inv1,
      l1w + 4*2304, nullptr, RA, partA, nullptr, nullptr, HB, 4, 32,32,32,32, 1,1, nx1);
  adder_q<4,1,false,false><<<G1,256,0,stream>>>(RA, nullptr, partA, nx1, nullptr, 0, inv1,
      l1w + 5*2304, nullptr, RB0, partB0, nullptr, nullptr, nullptr, 4, 32,32,32,32, 1,1, nx1);

  // ---- layer2 (CoutQ=8, 16x16)
  adder_q<4,2,true ,false><<<G2,256,0,stream>>>(RB0, HB, partB0, nx1, nullptr, 0, inv1,
      l2w0, l2down, RA, partA, RD, partD, nullptr, 8, 32,32,16,16, 2,1, nx2);
  adder_q<8,1,false,false><<<G2,256,0,stream>>>(RA, nullptr, partA, nx2, nullptr, 0, inv2,
      l2ws + 0*9216, nullptr, RB1, partB1, nullptr, nullptr, nullptr, 8, 16,16,16,16, 1,1, nx2);
  adder_q<8,3,false,true ><<<G2,256,0,stream>>>(RB1, RD, partB1, nx2, partD, nx2, inv2,
      l2ws + 1*9216, nullptr, RA, partA, nullptr, nullptr, HA, 8, 16,16,16,16, 1,1, nx2);
  adder_q<8,1,false,false><<<G2,256,0,stream>>>(RA, nullptr, partA, nx2, nullptr, 0, inv2,
      l2ws + 2*9216, nullptr, RB0, partB0, nullptr, nullptr, nullptr, 8, 16,16,16,16, 1,1, nx2);
  adder_q<8,2,false,true ><<<G2,256,0,stream>>>(RB0, HA, partB0, nx2, nullptr, 0, inv2,
      l2ws + 3*9216, nullptr, RA, partA, nullptr, nullptr, HB, 8, 16,16,16,16, 1,1, nx2);
  adder_q<8,1,false,false><<<G2,256,0,stream>>>(RA, nullptr, partA, nx2, nullptr, 0, inv2,
      l2ws + 4*9216, nullptr, RB1, partB1, nullptr, nullptr, nullptr, 8, 16,16,16,16, 1,1, nx2);

  // ---- layer3 (CoutQ=16, 8x8)
  adder_q<8,2,true ,false><<<G3,256,0,stream>>>(RB1, HB, partB1, nx2, nullptr, 0, inv2,
      l3w0, l3down, RA, partA, RD, partD, nullptr, 16, 16,16,8,8, 2,1, nx3);
  adder_q<16,1,false,false><<<G3,256,0,stream>>>(RA, nullptr, partA, nx3, nullptr, 0, inv3,
      l3ws + 0*36864, nullptr, RB0, partB0, nullptr, nullptr, nullptr, 16, 8,8,8,8, 1,1, nx3);
  adder_q<16,3,false,true ><<<G3,256,0,stream>>>(RB0, RD, partB0, nx3, partD, nx3, inv3,
      l3ws + 1*36864, nullptr, RA, partA, nullptr, nullptr, HA, 16, 8,8,8,8, 1,1, nx3);
  adder_q<16,1,false,false><<<G3,256,0,stream>>>(RA, nullptr, partA, nx3, nullptr, 0, inv3,
      l3ws + 2*36864, nullptr, RB1, partB1, nullptr, nullptr, nullptr, 16, 8,8,8,8, 1,1, nx3);
  adder_q<16,2,false,true ><<<G3,256,0,stream>>>(RB1, HA, partB1, nx3, nullptr, 0, inv3,
      l3ws + 3*36864, nullptr, RA, partA, nullptr, nullptr, HB, 16, 8,8,8,8, 1,1, nx3);
  adder_q<16,1,false,false><<<G3,256,0,stream>>>(RA, nullptr, partA, nx3, nullptr, 0, inv3,
      l3ws + 4*36864, nullptr, RB0, partB0, nullptr, nullptr, nullptr, 16, 8,8,8,8, 1,1, nx3);

  // final combine + pool, head
  pool_combine<<<32, 256, 0, stream>>>(RB0, partB0, HB, inv3, pooled);
  head_k<<<1, 320, 0, stream>>>(pooled, fcw, out);
}

// Round 13
// 604.559 us; speedup vs baseline: 4.2171x; 1.5704x over previous
//
#include <hip/hip_runtime.h>

#define BN_EPS 1e-5f

// Activations in NCHW4c: elem(b,c,p) at [((b*(C/4) + c/4)*HW + p)*4 + (c&3)].
// Weights as given: [Cout][Cin][3][3]; 1x1 down weights [Cout][Cin].

// ---------------- stats prologue: [C][nPart] (sum,sumsq) -> smr[c]=(rstd, -mean*rstd)
template<int C>
__device__ __forceinline__ void stats_prologue(const float2* __restrict__ part,
                                               int nPart, float invN,
                                               float2* smr, float2* pred) {
  const int TPC = 256 / C;
  int c  = threadIdx.x / TPC;
  int sl = threadIdx.x - c * TPC;
  float s = 0.f, s2 = 0.f;
  for (int j = sl; j < nPart; j += TPC) {
    float2 p = part[c * nPart + j];
    s += p.x; s2 += p.y;
  }
  pred[threadIdx.x] = make_float2(s, s2);
  __syncthreads();
  for (int st = TPC >> 1; st; st >>= 1) {
    if (sl < st) {
      pred[threadIdx.x].x += pred[threadIdx.x + st].x;
      pred[threadIdx.x].y += pred[threadIdx.x + st].y;
    }
    __syncthreads();
  }
  if (sl == 0) {
    float m   = pred[threadIdx.x].x * invN;
    float var = fmaxf(pred[threadIdx.x].y * invN - m * m, 0.f);
    float r   = rsqrtf(var + BN_EPS);
    smr[c] = make_float2(r, -m * r);
  }
  __syncthreads();
}

// Virtual-input transform (in-bounds taps only; OOB taps stay 0 — activation
// precedes patch extraction, so zero padding contributes |0-w|):
//  0: a; 1: relu(bnA(a)); 2: relu(bnA(a)+b); 3: relu(bnA(a)+bnB(b));
//  4: relu(bnA(a)+relu(bnB(b)))
template<int INM>
__device__ __forceinline__ float xf(float a, float b, float2 tA, float2 tB) {
  if (INM == 0) return a;
  if (INM == 1) return fmaxf(fmaf(a, tA.x, tA.y), 0.f);
  if (INM == 2) return fmaxf(fmaf(a, tA.x, tA.y) + b, 0.f);
  if (INM == 3) return fmaxf(fmaf(a, tA.x, tA.y) + fmaf(b, tB.x, tB.y), 0.f);
  /* 4 */        return fmaxf(fmaf(a, tA.x, tA.y) + fmaxf(fmaf(b, tB.x, tB.y), 0.f), 0.f);
}

// ---------------- unified adder (all layers)
// Block = 256 thr = 4 waves x 64 positions. Wave zw handles ci-quads
// [zw*WQ, (zw+1)*WQ), one quad per iteration (#pragma unroll 1: one q[9]
// float4 patch live). One co-quad per block.
// __launch_bounds__(256,2): (256,4) empirically pins the allocator to exactly
// 64 VGPRs (r8-r12, three different bodies) and the ~90-reg live set spills
// to scratch (FETCH/WRITE MBs per dispatch). (256,2) doubles the budget.
// Grid 1D = nx * CoutQ, XCD-swizzled. LDS float4 reduce over waves; wave 0
// writes raw (float4, coalesced) + per-(block,channel) BN partials.
// DOWN: fused 1x1 stride-2 adder via always-valid center tap.
// HWRITE (stride-1, coq==0): each wave writes its transformed ci-quads to hout.
template<int CQ, int INM, bool DOWN, bool HWRITE>
__global__ void __launch_bounds__(256, 2)
adder_q(const float* __restrict__ A, const float* __restrict__ Bt,
        const float2* __restrict__ pA, int nPA,
        const float2* __restrict__ pB, int nPB, float invNin,
        const float* __restrict__ w, const float* __restrict__ wD,
        float* __restrict__ raw, float2* __restrict__ parts,
        float* __restrict__ rawD, float2* __restrict__ partsD,
        float* __restrict__ hout,
        int CoutQ, int H, int W, int Ho, int Wo, int stride, int pad, int nx) {
  constexpr int CIN = CQ * 4;
  constexpr int WQ  = CQ / 4;
  __shared__ float2 pred[256];
  __shared__ float2 smA[(INM >= 1) ? CIN : 1];
  __shared__ float2 smB[(INM >= 3) ? CIN : 1];
  __shared__ float4 sacc[4][64];
  __shared__ float4 saccD[DOWN ? 4 : 1][DOWN ? 64 : 1];
  if (INM >= 1) stats_prologue<CIN>(pA, nPA, invNin, smA, pred);
  if (INM >= 3) stats_prologue<CIN>(pB, nPB, invNin, smB, pred);

  const int id = blockIdx.x, span = nx >> 3;
  const int xcd = id & 7, slot = id >> 3;
  const int pc  = xcd * span + slot % span;
  const int coq = slot / span;

  const int HW = H * W, HWo = Ho * Wo;
  const int zw = threadIdx.x >> 6, pl = threadIdx.x & 63;
  const int i  = pc * 64 + pl;
  const int b  = i / HWo, hw = i - b * HWo;
  const int ho = hw / Wo, wo = hw - ho * Wo;

  int off[9]; bool val[9];
  #pragma unroll
  for (int kh = 0; kh < 3; kh++) {
    int hh = ho * stride + kh - pad;
    bool hv = (hh >= 0) & (hh < H);
    #pragma unroll
    for (int kw = 0; kw < 3; kw++) {
      int ww = wo * stride + kw - pad;
      val[kh * 3 + kw] = hv & (ww >= 0) & (ww < W);
      off[kh * 3 + kw] = hh * W + ww;
    }
  }

  float acc[4]  = {0.f, 0.f, 0.f, 0.f};
  float accD[4] = {0.f, 0.f, 0.f, 0.f};

  #pragma unroll 1
  for (int wq = 0; wq < WQ; wq++) {
    const int cq = zw * WQ + wq;
    const float* Ab = A + (size_t)(b * CQ + cq) * HW * 4;
    const float* Bb = (INM >= 2) ? (Bt + (size_t)(b * CQ + cq) * HW * 4) : nullptr;
    float2 tA0, tA1, tA2, tA3, tB0, tB1, tB2, tB3;
    if (INM >= 1) { tA0 = smA[cq*4]; tA1 = smA[cq*4+1]; tA2 = smA[cq*4+2]; tA3 = smA[cq*4+3]; }
    if (INM >= 3) { tB0 = smB[cq*4]; tB1 = smB[cq*4+1]; tB2 = smB[cq*4+2]; tB3 = smB[cq*4+3]; }
    float4 q[9];
    #pragma unroll
    for (int t = 0; t < 9; t++) {
      float4 a4 = make_float4(0.f, 0.f, 0.f, 0.f);
      if (val[t]) {
        a4 = *reinterpret_cast<const float4*>(Ab + (size_t)off[t] * 4);
        if (INM >= 1) {
          float4 b4 = make_float4(0.f, 0.f, 0.f, 0.f);
          if (INM >= 2) b4 = *reinterpret_cast<const float4*>(Bb + (size_t)off[t] * 4);
          a4.x = xf<INM>(a4.x, b4.x, tA0, tB0);
          a4.y = xf<INM>(a4.y, b4.y, tA1, tB1);
          a4.z = xf<INM>(a4.z, b4.z, tA2, tB2);
          a4.w = xf<INM>(a4.w, b4.w, tA3, tB3);
        }
      }
      q[t] = a4;
    }
    if (HWRITE) {
      if (coq == 0)
        *reinterpret_cast<float4*>(hout + ((size_t)(b * CQ + cq) * HW + hw) * 4) = q[4];
    }
    #pragma unroll
    for (int c = 0; c < 4; c++) {
      const float* wp = w + ((coq * 4 + c) * CIN + cq * 4) * 9;   // wave-uniform
      float a = 0.f;
      #pragma unroll
      for (int t = 0; t < 9; t++) {
        a += fabsf(q[t].x - wp[t])      + fabsf(q[t].y - wp[9 + t])
           + fabsf(q[t].z - wp[18 + t]) + fabsf(q[t].w - wp[27 + t]);
      }
      acc[c] += a;
      if (DOWN) {
        const float* wd = wD + (coq * 4 + c) * CIN + cq * 4;
        accD[c] += fabsf(q[4].x - wd[0]) + fabsf(q[4].y - wd[1])
                 + fabsf(q[4].z - wd[2]) + fabsf(q[4].w - wd[3]);
      }
    }
  }

  sacc[zw][pl] = make_float4(acc[0], acc[1], acc[2], acc[3]);
  if (DOWN) saccD[zw][pl] = make_float4(accD[0], accD[1], accD[2], accD[3]);
  __syncthreads();
  if (zw == 0) {
    float4 q0 = sacc[0][pl], q1 = sacc[1][pl], q2 = sacc[2][pl], q3 = sacc[3][pl];
    float4 v = make_float4(-(q0.x + q1.x + q2.x + q3.x), -(q0.y + q1.y + q2.y + q3.y),
                           -(q0.z + q1.z + q2.z + q3.z), -(q0.w + q1.w + q2.w + q3.w));
    *reinterpret_cast<float4*>(raw + ((size_t)(b * CoutQ + coq) * HWo + hw) * 4) = v;
    float s[4] = {v.x, v.y, v.z, v.w};
    #pragma unroll
    for (int c = 0; c < 4; c++) {
      float sx = s[c], sy = s[c] * s[c];
      #pragma unroll
      for (int o = 32; o; o >>= 1) { sx += __shfl_down(sx, o, 64); sy += __shfl_down(sy, o, 64); }
      if (pl == 0) parts[(coq * 4 + c) * nx + pc] = make_float2(sx, sy);
    }
    if (DOWN) {
      float4 d0 = saccD[0][pl], d1 = saccD[1][pl], d2 = saccD[2][pl], d3 = saccD[3][pl];
      float4 vd = make_float4(-(d0.x + d1.x + d2.x + d3.x), -(d0.y + d1.y + d2.y + d3.y),
                              -(d0.z + d1.z + d2.z + d3.z), -(d0.w + d1.w + d2.w + d3.w));
      *reinterpret_cast<float4*>(rawD + ((size_t)(b * CoutQ + coq) * HWo + hw) * 4) = vd;
      float sd[4] = {vd.x, vd.y, vd.z, vd.w};
      #pragma unroll
      for (int c = 0; c < 4; c++) {
        float sx = sd[c], sy = sd[c] * sd[c];
        #pragma unroll
        for (int o = 32; o; o >>= 1) { sx += __shfl_down(sx, o, 64); sy += __shfl_down(sy, o, 64); }
        if (pl == 0) partsD[(coq * 4 + c) * nx + pc] = make_float2(sx, sy);
      }
    }
  }
}

// ---------------- conv stem (NCHW in) -> NCHW4c raw + per-block BN partials [16][128]
__global__ void __launch_bounds__(256)
conv_stem_bn(const float* __restrict__ x, const float* __restrict__ w,
             float* __restrict__ raw, float2* __restrict__ partials) {
  const int i = blockIdx.x * 256 + threadIdx.x;   // position, b-major (32768)
  const int b = i >> 10, hw = i & 1023;
  const int ho = hw >> 5, wo = hw & 31;
  float xv[27];
  #pragma unroll
  for (int ci = 0; ci < 3; ci++) {
    const float* xp = x + (b * 3 + ci) * 1024;
    #pragma unroll
    for (int kh = 0; kh < 3; kh++) {
      int hh = ho + kh - 1;
      bool hv = (hh >= 0) & (hh < 32);
      #pragma unroll
      for (int kw = 0; kw < 3; kw++) {
        int ww = wo + kw - 1;
        xv[(ci * 3 + kh) * 3 + kw] = (hv & (ww >= 0) & (ww < 32)) ? xp[hh * 32 + ww] : 0.f;
      }
    }
  }
  float acc[16];
  #pragma unroll
  for (int co = 0; co < 16; co++) {
    float a = 0.f;
    const float* wp = w + co * 27;
    #pragma unroll
    for (int t = 0; t < 27; t++) a += xv[t] * wp[t];
    acc[co] = a;
  }
  #pragma unroll
  for (int cq = 0; cq < 4; cq++)
    *reinterpret_cast<float4*>(raw + ((size_t)(b * 4 + cq) * 1024 + hw) * 4) =
        make_float4(acc[cq * 4], acc[cq * 4 + 1], acc[cq * 4 + 2], acc[cq * 4 + 3]);

  __shared__ float2 red[4][16];
  const int lane = threadIdx.x & 63, wid = threadIdx.x >> 6;
  #pragma unroll
  for (int co = 0; co < 16; co++) {
    float sx = acc[co], sy = acc[co] * acc[co];
    #pragma unroll
    for (int o = 32; o; o >>= 1) { sx += __shfl_down(sx, o, 64); sy += __shfl_down(sy, o, 64); }
    if (lane == 0) red[wid][co] = make_float2(sx, sy);
  }
  __syncthreads();
  if (threadIdx.x < 16) {
    float2 t = red[0][threadIdx.x];
    #pragma unroll
    for (int wv = 1; wv < 4; wv++) { t.x += red[wv][threadIdx.x].x; t.y += red[wv][threadIdx.x].y; }
    partials[threadIdx.x * 128 + blockIdx.x] = t;
  }
}

// ---------------- final combine + per-image pool (NCHW4c in, grid 32 = images)
__global__ void __launch_bounds__(256)
pool_combine(const float* __restrict__ raw2, const float2* __restrict__ part2,
             const float* __restrict__ idsrc, float invN, float* __restrict__ pooled) {
  __shared__ float2 s2[64];
  __shared__ float2 pred[256];
  __shared__ float4 s4[16][16];
  stats_prologue<64>(part2, 32, invN, s2, pred);
  const int b = blockIdx.x, cq = threadIdx.x & 15, pg = threadIdx.x >> 4;
  float2 t0 = s2[cq * 4], t1 = s2[cq * 4 + 1], t2 = s2[cq * 4 + 2], t3 = s2[cq * 4 + 3];
  float4 sum = make_float4(0.f, 0.f, 0.f, 0.f);
  #pragma unroll
  for (int k = 0; k < 4; k++) {
    int pos = pg * 4 + k;
    size_t idx = ((size_t)(b * 16 + cq) * 64 + pos) * 4;
    float4 r = *reinterpret_cast<const float4*>(raw2 + idx);
    float4 d = *reinterpret_cast<const float4*>(idsrc + idx);
    sum.x += fmaxf(fmaf(r.x, t0.x, t0.y) + d.x, 0.f);
    sum.y += fmaxf(fmaf(r.y, t1.x, t1.y) + d.y, 0.f);
    sum.z += fmaxf(fmaf(r.z, t2.x, t2.y) + d.z, 0.f);
    sum.w += fmaxf(fmaf(r.w, t3.x, t3.y) + d.w, 0.f);
  }
  s4[pg][cq] = sum;
  __syncthreads();
  if (threadIdx.x < 64) {
    const int c = threadIdx.x, cq2 = c >> 2, j = c & 3;
    float s = 0.f;
    #pragma unroll
    for (int g = 0; g < 16; g++) {
      float4 t = s4[g][cq2];
      s += (j == 0) ? t.x : (j == 1) ? t.y : (j == 2) ? t.z : t.w;
    }
    pooled[b * 64 + c] = s * (1.f / 64.f);
  }
}

// ---------------- head
__global__ void head_k(const float* __restrict__ pooled, const float* __restrict__ fcw,
                       float* __restrict__ out) {
  __shared__ float logits[320];
  __shared__ float mn[10], rs[10];
  int t = threadIdx.x;
  if (t < 320) {
    int b = t / 10, o = t - b * 10;
    float s = 0.f;
    #pragma unroll
    for (int c = 0; c < 64; c++) s += pooled[b * 64 + c] * fcw[o * 64 + c];
    logits[t] = s;
  }
  __syncthreads();
  if (t < 10) {
    float s = 0.f;
    for (int b = 0; b < 32; b++) s += logits[b * 10 + t];
    float m = s * (1.f / 32.f);
    float v = 0.f;
    for (int b = 0; b < 32; b++) { float d = logits[b * 10 + t] - m; v += d * d; }
    mn[t] = m;
    rs[t] = rsqrtf(v * (1.f / 32.f) + BN_EPS);
  }
  __syncthreads();
  if (t < 320) out[t] = (logits[t] - mn[t % 10]) * rs[t % 10];
}

// ================================================================ host
extern "C" void kernel_launch(void* const* d_in, const int* in_sizes, int n_in,
                              void* d_out, int out_size, void* d_ws, size_t ws_size,
                              hipStream_t stream) {
  const float* x      = (const float*)d_in[0];
  const float* conv1w = (const float*)d_in[1];
  const float* l1w    = (const float*)d_in[2];
  const float* l2w0   = (const float*)d_in[3];
  const float* l2ws   = (const float*)d_in[4];
  const float* l2down = (const float*)d_in[5];
  const float* l3w0   = (const float*)d_in[6];
  const float* l3ws   = (const float*)d_in[7];
  const float* l3down = (const float*)d_in[8];
  const float* fcw    = (const float*)d_in[9];
  float* out = (float*)d_out;

  const int S = 524288;                    // 2 MB in floats
  float* base = (float*)d_ws;
  float* R0  = base + 0 * S;               // stem raw
  float* RA  = base + 1 * S;               // a1 raw (transient)
  float* RB0 = base + 2 * S;               // a2 raw dbuf
  float* RB1 = base + 3 * S;
  float* HA  = base + 4 * S;               // h dbuf
  float* HB  = base + 5 * S;
  float* RD  = base + 6 * S;               // down raw
  float* pooled = base + 7 * S;            // 2048
  float2* partS  = (float2*)(pooled + 4096);  // [16][128]
  float2* partA  = partS  + 8192;             // up to [16][512]
  float2* partB0 = partA  + 8192;
  float2* partB1 = partB0 + 8192;
  float2* partD  = partB1 + 8192;

  const float inv1 = 1.f / 32768.f, inv2 = 1.f / 8192.f, inv3 = 1.f / 2048.f;
  const int nx1 = 512, nx2 = 128, nx3 = 32;             // B*HWo/64
  const int G1 = nx1 * 4, G2 = nx2 * 8, G3 = nx3 * 16;  // 2048 / 1024 / 512

  // 1. stem
  conv_stem_bn<<<128, 256, 0, stream>>>(x, conv1w, R0, partS);

  // ---- layer1 (CQ=4, CoutQ=4, 32x32)
  adder_q<4,1,false,false><<<G1,256,0,stream>>>(R0, nullptr, partS, 128, nullptr, 0, inv1,
      l1w + 0*2304, nullptr, RA, partA, nullptr, nullptr, nullptr, 4, 32,32,32,32, 1,1, nx1);
  adder_q<4,1,false,false><<<G1,256,0,stream>>>(RA, nullptr, partA, nx1, nullptr, 0, inv1,
      l1w + 1*2304, nullptr, RB0, partB0, nullptr, nullptr, nullptr, 4, 32,32,32,32, 1,1, nx1);
  adder_q<4,4,false,true ><<<G1,256,0,stream>>>(RB0, R0, partB0, nx1, partS, 128, inv1,
      l1w + 2*2304, nullptr, RA, partA, nullptr, nullptr, HA, 4, 32,32,32,32, 1,1, nx1);
  adder_q<4,1,false,false><<<G1,256,0,stream>>>(RA, nullptr, partA, nx1, nullptr, 0, inv1,
      l1w + 3*2304, nullptr, RB1, partB1, nullptr, nullptr, nullptr, 4, 32,32,32,32, 1,1, nx1);
  adder_q<4,2,false,true ><<<G1,256,0,stream>>>(RB1, HA, partB1, nx1, nullptr, 0, inv1,
      l1w + 4*2304, nullptr, RA, partA, nullptr, nullptr, HB, 4, 32,32,32,32, 1,1, nx1);
  adder_q<4,1,false,false><<<G1,256,0,stream>>>(RA, nullptr, partA, nx1, nullptr, 0, inv1,
      l1w + 5*2304, nullptr, RB0, partB0, nullptr, nullptr, nullptr, 4, 32,32,32,32, 1,1, nx1);

  // ---- layer2 (CoutQ=8, 16x16)
  adder_q<4,2,true ,false><<<G2,256,0,stream>>>(RB0, HB, partB0, nx1, nullptr, 0, inv1,
      l2w0, l2down, RA, partA, RD, partD, nullptr, 8, 32,32,16,16, 2,1, nx2);
  adder_q<8,1,false,false><<<G2,256,0,stream>>>(RA, nullptr, partA, nx2, nullptr, 0, inv2,
      l2ws + 0*9216, nullptr, RB1, partB1, nullptr, nullptr, nullptr, 8, 16,16,16,16, 1,1, nx2);
  adder_q<8,3,false,true ><<<G2,256,0,stream>>>(RB1, RD, partB1, nx2, partD, nx2, inv2,
      l2ws + 1*9216, nullptr, RA, partA, nullptr, nullptr, HA, 8, 16,16,16,16, 1,1, nx2);
  adder_q<8,1,false,false><<<G2,256,0,stream>>>(RA, nullptr, partA, nx2, nullptr, 0, inv2,
      l2ws + 2*9216, nullptr, RB0, partB0, nullptr, nullptr, nullptr, 8, 16,16,16,16, 1,1, nx2);
  adder_q<8,2,false,true ><<<G2,256,0,stream>>>(RB0, HA, partB0, nx2, nullptr, 0, inv2,
      l2ws + 3*9216, nullptr, RA, partA, nullptr, nullptr, HB, 8, 16,16,16,16, 1,1, nx2);
  adder_q<8,1,false,false><<<G2,256,0,stream>>>(RA, nullptr, partA, nx2, nullptr, 0, inv2,
      l2ws + 4*9216, nullptr, RB1, partB1, nullptr, nullptr, nullptr, 8, 16,16,16,16, 1,1, nx2);

  // ---- layer3 (CoutQ=16, 8x8)
  adder_q<8,2,true ,false><<<G3,256,0,stream>>>(RB1, HB, partB1, nx2, nullptr, 0, inv2,
      l3w0, l3down, RA, partA, RD, partD, nullptr, 16, 16,16,8,8, 2,1, nx3);
  adder_q<16,1,false,false><<<G3,256,0,stream>>>(RA, nullptr, partA, nx3, nullptr, 0, inv3,
      l3ws + 0*36864, nullptr, RB0, partB0, nullptr, nullptr, nullptr, 16, 8,8,8,8, 1,1, nx3);
  adder_q<16,3,false,true ><<<G3,256,0,stream>>>(RB0, RD, partB0, nx3, partD, nx3, inv3,
      l3ws + 1*36864, nullptr, RA, partA, nullptr, nullptr, HA, 16, 8,8,8,8, 1,1, nx3);
  adder_q<16,1,false,false><<<G3,256,0,stream>>>(RA, nullptr, partA, nx3, nullptr, 0, inv3,
      l3ws + 2*36864, nullptr, RB1, partB1, nullptr, nullptr, nullptr, 16, 8,8,8,8, 1,1, nx3);
  adder_q<16,2,false,true ><<<G3,256,0,stream>>>(RB1, HA, partB1, nx3, nullptr, 0, inv3,
      l3ws + 3*36864, nullptr, RA, partA, nullptr, nullptr, HB, 16, 8,8,8,8, 1,1, nx3);
  adder_q<16,1,false,false><<<G3,256,0,stream>>>(RA, nullptr, partA, nx3, nullptr, 0, inv3,
      l3ws + 4*36864, nullptr, RB0, partB0, nullptr, nullptr, nullptr, 16, 8,8,8,8, 1,1, nx3);

  // final combine + pool, head
  pool_combine<<<32, 256, 0, stream>>>(RB0, partB0, HB, inv3, pooled);
  head_k<<<1, 320, 0, stream>>>(pooled, fcw, out);
}